// Round 1
// baseline (2346.661 us; speedup 1.0000x reference)
//
#include <hip/hip_runtime.h>
#include <cfloat>

#define N_NODES 50000
#define N_EDGES 600000
#define DIM 128
#define N_GRAPHS 256
#define HIDDEN 256
#define OUT_DIM 16
#define MAX_DEG 10
#define MAX_TBL 1600

// ---------------- CSR build ----------------
__global__ void k_deg_count(const int* __restrict__ col, int* __restrict__ deg) {
  int e = blockIdx.x * blockDim.x + threadIdx.x;
  if (e < N_EDGES) atomicAdd(&deg[col[e]], 1);
}

__global__ void k_scan(const int* __restrict__ deg, int* __restrict__ rowptr,
                       int* __restrict__ cursor) {
  __shared__ int tsum[1024];
  const int CH = (N_NODES + 1023) / 1024;  // 49
  int t = threadIdx.x;
  int lo = t * CH, hi = min(lo + CH, N_NODES);
  int s = 0;
  for (int i = lo; i < hi; ++i) s += deg[i];
  tsum[t] = s;
  __syncthreads();
  for (int off = 1; off < 1024; off <<= 1) {
    int v = (t >= off) ? tsum[t - off] : 0;
    __syncthreads();
    tsum[t] += v;
    __syncthreads();
  }
  int pre = (t == 0) ? 0 : tsum[t - 1];
  for (int i = lo; i < hi; ++i) { rowptr[i] = pre; cursor[i] = pre; pre += deg[i]; }
  if (t == 1023) rowptr[N_NODES] = tsum[1023];
}

__global__ void k_csr_scatter(const int* __restrict__ row, const int* __restrict__ col,
                              int* __restrict__ cursor, int* __restrict__ src) {
  int e = blockIdx.x * blockDim.x + threadIdx.x;
  if (e < N_EDGES) {
    int p = atomicAdd(&cursor[col[e]], 1);
    src[p] = row[e];
  }
}

__global__ void k_bucket_count(const int* __restrict__ deg, int* __restrict__ bcnt) {
  int i = blockIdx.x * blockDim.x + threadIdx.x;
  if (i < N_NODES) atomicAdd(&bcnt[min(deg[i], MAX_DEG)], 1);
}

__global__ void k_bucket_table(const int* __restrict__ bcnt, int* __restrict__ bcur,
                               int* __restrict__ tbl_d, int* __restrict__ tbl_base,
                               int* __restrict__ tbl_cnt) {
  if (threadIdx.x == 0 && blockIdx.x == 0) {
    int off = 0, nb = 0;
    for (int d = 0; d <= MAX_DEG; ++d) {
      bcur[d] = off;
      int c = bcnt[d];
      for (int s = 0; s < c; s += 32) {
        tbl_d[nb] = d; tbl_base[nb] = off + s; tbl_cnt[nb] = min(32, c - s); nb++;
      }
      off += c;
    }
    for (; nb < MAX_TBL; ++nb) tbl_d[nb] = -1;
  }
}

__global__ void k_node_scatter(const int* __restrict__ deg, int* __restrict__ bcur,
                               int* __restrict__ nlist) {
  int i = blockIdx.x * blockDim.x + threadIdx.x;
  if (i < N_NODES) {
    int p = atomicAdd(&bcur[min(deg[i], MAX_DEG)], 1);
    nlist[p] = i;
  }
}

// ---------------- Aggregations ----------------
// h[i] = sum over incoming edges of (relu?)(x[src])
template <bool RELU>
__global__ void k_agg_sum(const float* __restrict__ x, const int* __restrict__ rowptr,
                          const int* __restrict__ src, float* __restrict__ h) {
  int node = blockIdx.x * 4 + (threadIdx.x >> 5);
  int l = threadIdx.x & 31;
  if (node >= N_NODES) return;
  int s = rowptr[node], e = rowptr[node + 1];
  float4 acc = make_float4(0.f, 0.f, 0.f, 0.f);
  for (int p = s; p < e; ++p) {
    const float4 v = ((const float4*)(x + (size_t)src[p] * DIM))[l];
    if (RELU) {
      acc.x += fmaxf(v.x, 0.f); acc.y += fmaxf(v.y, 0.f);
      acc.z += fmaxf(v.z, 0.f); acc.w += fmaxf(v.w, 0.f);
    } else {
      acc.x += v.x; acc.y += v.y; acc.z += v.z; acc.w += v.w;
    }
  }
  ((float4*)(h + (size_t)node * DIM))[l] = acc;
}

// out[i] = (deg==0) ? 0 : C[i] + b_edge + max_{incoming} B[src]
__global__ void k_edge_aggr(const float* __restrict__ Bm, const float* __restrict__ Cm,
                            const float* __restrict__ b_edge, const int* __restrict__ deg,
                            const int* __restrict__ rowptr, const int* __restrict__ src,
                            float* __restrict__ out) {
  int node = blockIdx.x * 4 + (threadIdx.x >> 5);
  int l = threadIdx.x & 31;
  if (node >= N_NODES) return;
  float4* o = (float4*)(out + (size_t)node * DIM);
  if (deg[node] == 0) { o[l] = make_float4(0.f, 0.f, 0.f, 0.f); return; }
  int s = rowptr[node], e = rowptr[node + 1];
  float4 m = make_float4(-FLT_MAX, -FLT_MAX, -FLT_MAX, -FLT_MAX);
  for (int p = s; p < e; ++p) {
    const float4 v = ((const float4*)(Bm + (size_t)src[p] * DIM))[l];
    m.x = fmaxf(m.x, v.x); m.y = fmaxf(m.y, v.y);
    m.z = fmaxf(m.z, v.z); m.w = fmaxf(m.w, v.w);
  }
  const float4 c = ((const float4*)(Cm + (size_t)node * DIM))[l];
  const float4 be = ((const float4*)b_edge)[l];
  o[l] = make_float4(c.x + be.x + m.x, c.y + be.y + m.y,
                     c.z + be.z + m.z, c.w + be.w + m.w);
}

// ---------------- MFConv matvec (degree-bucketed, 32 nodes / block) ----------------
template <bool RELUX>
__global__ __launch_bounds__(128) void k_mfconv(
    const float* __restrict__ h, const float* __restrict__ x,
    const float* __restrict__ W_lin, const float* __restrict__ b_lin,
    const float* __restrict__ W_root,
    const int* __restrict__ tbl_d, const int* __restrict__ tbl_base,
    const int* __restrict__ tbl_cnt, const int* __restrict__ nlist,
    float* __restrict__ out) {
  int b = blockIdx.x;
  int d = tbl_d[b];
  if (d < 0) return;
  int base = tbl_base[b], cnt = tbl_cnt[b];
  __shared__ float hs[32][DIM];
  __shared__ float xs[32][DIM];
  __shared__ int nid[32];
  int j = threadIdx.x;
  if (j < 32) nid[j] = nlist[base + min(j, cnt - 1)];
  __syncthreads();
#pragma unroll 4
  for (int i = 0; i < 32; ++i) {
    size_t r = (size_t)nid[i] * DIM + j;
    float hv = h[r], xv = x[r];
    if (RELUX) xv = fmaxf(xv, 0.f);
    hs[i][j] = hv; xs[i][j] = xv;
  }
  __syncthreads();
  const float* Wl = W_lin + (size_t)d * DIM * DIM + j;
  const float* Wr = W_root + (size_t)d * DIM * DIM + j;
  float bl = b_lin[d * DIM + j];
  float acc[32];
#pragma unroll
  for (int i = 0; i < 32; ++i) acc[i] = bl;
  for (int k = 0; k < DIM; k += 4) {
    float wl0 = Wl[(k + 0) * DIM], wl1 = Wl[(k + 1) * DIM];
    float wl2 = Wl[(k + 2) * DIM], wl3 = Wl[(k + 3) * DIM];
    float wr0 = Wr[(k + 0) * DIM], wr1 = Wr[(k + 1) * DIM];
    float wr2 = Wr[(k + 2) * DIM], wr3 = Wr[(k + 3) * DIM];
#pragma unroll
    for (int i = 0; i < 32; ++i) {
      float4 hv = *(const float4*)&hs[i][k];
      float4 xv = *(const float4*)&xs[i][k];
      acc[i] += hv.x * wl0 + hv.y * wl1 + hv.z * wl2 + hv.w * wl3 +
                xv.x * wr0 + xv.y * wr1 + xv.z * wr2 + xv.w * wr3;
    }
  }
  for (int i = 0; i < 32; ++i)
    if (i < cnt) out[(size_t)nid[i] * DIM + j] = acc[i];
}

// ---------------- EdgeConv GEMM: B = e@W_bot, C = e@(W_top - W_bot) ----------------
template <bool RELU>
__global__ __launch_bounds__(128) void k_edge_gemm(
    const float* __restrict__ e, const float* __restrict__ W,
    float* __restrict__ Bm, float* __restrict__ Cm) {
  int base = blockIdx.x * 32;
  int j = threadIdx.x;
  int cnt = min(32, N_NODES - base);
  __shared__ float es[32][DIM];
#pragma unroll 4
  for (int i = 0; i < 32; ++i) {
    int r = base + min(i, cnt - 1);
    float v = e[(size_t)r * DIM + j];
    if (RELU) v = fmaxf(v, 0.f);
    es[i][j] = v;
  }
  __syncthreads();
  float accB[32], accC[32];
#pragma unroll
  for (int i = 0; i < 32; ++i) { accB[i] = 0.f; accC[i] = 0.f; }
  const float* Wt = W + j;              // rows [0,128)   = W_top
  const float* Wb = W + 128 * DIM + j;  // rows [128,256) = W_bot
  for (int k = 0; k < DIM; k += 4) {
    float wb0 = Wb[(k + 0) * DIM], wb1 = Wb[(k + 1) * DIM];
    float wb2 = Wb[(k + 2) * DIM], wb3 = Wb[(k + 3) * DIM];
    float wd0 = Wt[(k + 0) * DIM] - wb0, wd1 = Wt[(k + 1) * DIM] - wb1;
    float wd2 = Wt[(k + 2) * DIM] - wb2, wd3 = Wt[(k + 3) * DIM] - wb3;
#pragma unroll
    for (int i = 0; i < 32; ++i) {
      float4 ev = *(const float4*)&es[i][k];
      accB[i] += ev.x * wb0 + ev.y * wb1 + ev.z * wb2 + ev.w * wb3;
      accC[i] += ev.x * wd0 + ev.y * wd1 + ev.z * wd2 + ev.w * wd3;
    }
  }
  for (int i = 0; i < 32; ++i)
    if (i < cnt) {
      Bm[(size_t)(base + i) * DIM + j] = accB[i];
      Cm[(size_t)(base + i) * DIM + j] = accC[i];
    }
}

// ---------------- Readout ----------------
__global__ void k_graph_bounds(const int* __restrict__ batch, int* __restrict__ gstart) {
  int g = blockIdx.x * blockDim.x + threadIdx.x;
  if (g > N_GRAPHS) return;
  int lo = 0, hi = N_NODES;
  while (lo < hi) {
    int mid = (lo + hi) >> 1;
    if (batch[mid] < g) lo = mid + 1; else hi = mid;
  }
  gstart[g] = lo;
}

__global__ void k_pool(const float* __restrict__ hf, const float* __restrict__ embE,
                       const int* __restrict__ deg, const int* __restrict__ gstart,
                       float* __restrict__ gf) {
  int g = blockIdx.x;
  int j = threadIdx.x;  // 256
  int s = gstart[g], e = gstart[g + 1];
  float acc = 0.f;
  if (j < DIM) {
    for (int i = s; i < e; ++i) acc += hf[(size_t)i * DIM + j];
  } else {
    int jj = j - DIM;
    for (int i = s; i < e; ++i)
      acc += (float)deg[i] * fmaxf(embE[(size_t)i * DIM + jj], 0.f);
  }
  gf[g * 256 + j] = acc;
}

__global__ void k_mlp0(const float* __restrict__ gf, const float* __restrict__ W0,
                       const float* __restrict__ b0, float* __restrict__ o) {
  int g = blockIdx.x, j = threadIdx.x;  // 256
  __shared__ float gs[256];
  gs[j] = gf[g * 256 + j];
  __syncthreads();
  float acc = b0[j];
  for (int k = 0; k < 256; ++k) acc += gs[k] * W0[k * 256 + j];
  o[g * 256 + j] = fmaxf(acc, 0.f);
}

__global__ void k_mlp1(const float* __restrict__ m0, const float* __restrict__ W1,
                       const float* __restrict__ b1, float* __restrict__ out) {
  int idx = blockIdx.x * 64 + threadIdx.x;
  if (idx >= N_GRAPHS * OUT_DIM) return;
  int g = idx >> 4, j = idx & 15;
  float acc = b1[j];
  const float* mr = m0 + g * HIDDEN;
  for (int k = 0; k < HIDDEN; ++k) acc += mr[k] * W1[k * OUT_DIM + j];
  out[idx] = fmaxf(acc, 0.f);
}

// ---------------- launch ----------------
extern "C" void kernel_launch(void* const* d_in, const int* in_sizes, int n_in,
                              void* d_out, int out_size, void* d_ws, size_t ws_size,
                              hipStream_t stream) {
  const float* x_in   = (const float*)d_in[0];
  const float* ea_in  = (const float*)d_in[1];
  const int*   ei     = (const int*)d_in[2];
  const int*   batch  = (const int*)d_in[3];
  const float* W_lin  = (const float*)d_in[4];
  const float* b_lin  = (const float*)d_in[5];
  const float* W_root = (const float*)d_in[6];
  const float* W_edge = (const float*)d_in[7];
  const float* b_edge = (const float*)d_in[8];
  const float* W0     = (const float*)d_in[9];
  const float* b0     = (const float*)d_in[10];
  const float* W1     = (const float*)d_in[11];
  const float* b1     = (const float*)d_in[12];
  const int* row = ei;
  const int* col = ei + N_EDGES;

  float* out0 = (float*)d_out;                  // [256,16]
  float* embN = out0 + N_GRAPHS * OUT_DIM;      // [50000,128] pre-relu MFConv out (iter 2)
  float* embE = embN + (size_t)N_NODES * DIM;   // [600000,128] pre-relu EdgeConv out (iter 2)

  char* wsp = (char*)d_ws;
  auto alloc = [&](size_t bytes) {
    char* p = wsp;
    wsp += (bytes + 255) & ~(size_t)255;
    return p;
  };
  int* deg      = (int*)alloc((size_t)N_NODES * 4);
  int* rowptr   = (int*)alloc((size_t)(N_NODES + 1) * 4);
  int* cursor   = (int*)alloc((size_t)N_NODES * 4);
  int* src      = (int*)alloc((size_t)N_EDGES * 4);
  int* nlist    = (int*)alloc((size_t)N_NODES * 4);
  int* bcnt     = (int*)alloc(16 * 4);
  int* bcur     = (int*)alloc(16 * 4);
  int* tbl_d    = (int*)alloc(MAX_TBL * 4);
  int* tbl_base = (int*)alloc(MAX_TBL * 4);
  int* tbl_cnt  = (int*)alloc(MAX_TBL * 4);
  int* gstart   = (int*)alloc(257 * 4);
  float* h      = (float*)alloc((size_t)N_NODES * DIM * 4);  // reused as h_final
  float* Bm     = (float*)alloc((size_t)N_NODES * DIM * 4);
  float* Cm     = (float*)alloc((size_t)N_NODES * DIM * 4);
  float* gf     = (float*)alloc((size_t)N_GRAPHS * 256 * 4);
  float* m0     = (float*)alloc((size_t)N_GRAPHS * HIDDEN * 4);

  hipMemsetAsync(deg, 0, (size_t)N_NODES * 4, stream);
  hipMemsetAsync(bcnt, 0, 16 * 4, stream);
  // emb_edge rows [50000, 600000) are exactly 0 (empty segment-max -> where -> 0)
  hipMemsetAsync(embE + (size_t)N_NODES * DIM, 0,
                 (size_t)(N_EDGES - N_NODES) * DIM * sizeof(float), stream);

  const int EB = (N_EDGES + 255) / 256;
  const int NB = (N_NODES + 255) / 256;
  k_deg_count<<<EB, 256, 0, stream>>>(col, deg);
  k_scan<<<1, 1024, 0, stream>>>(deg, rowptr, cursor);
  k_csr_scatter<<<EB, 256, 0, stream>>>(row, col, cursor, src);
  k_bucket_count<<<NB, 256, 0, stream>>>(deg, bcnt);
  k_bucket_table<<<1, 64, 0, stream>>>(bcnt, bcur, tbl_d, tbl_base, tbl_cnt);
  k_node_scatter<<<NB, 256, 0, stream>>>(deg, bcur, nlist);

  const int AGG_GRID = (N_NODES + 3) / 4;
  const int GEMM_GRID = (N_NODES + 31) / 32;
  // ---- message pass 0 ----
  k_agg_sum<false><<<AGG_GRID, 128, 0, stream>>>(x_in, rowptr, src, h);
  k_mfconv<false><<<MAX_TBL, 128, 0, stream>>>(h, x_in, W_lin, b_lin, W_root,
                                               tbl_d, tbl_base, tbl_cnt, nlist, embN);
  k_edge_gemm<false><<<GEMM_GRID, 128, 0, stream>>>(ea_in, W_edge, Bm, Cm);
  k_edge_aggr<<<AGG_GRID, 128, 0, stream>>>(Bm, Cm, b_edge, deg, rowptr, src, embE);
  // ---- message pass 1 (relu on read; in-place on d_out regions is block-local safe) ----
  k_agg_sum<true><<<AGG_GRID, 128, 0, stream>>>(embN, rowptr, src, h);
  k_mfconv<true><<<MAX_TBL, 128, 0, stream>>>(h, embN, W_lin, b_lin, W_root,
                                              tbl_d, tbl_base, tbl_cnt, nlist, embN);
  k_edge_gemm<true><<<GEMM_GRID, 128, 0, stream>>>(embE, W_edge, Bm, Cm);
  k_edge_aggr<<<AGG_GRID, 128, 0, stream>>>(Bm, Cm, b_edge, deg, rowptr, src, embE);
  // ---- readout ----
  k_agg_sum<true><<<AGG_GRID, 128, 0, stream>>>(embN, rowptr, src, h);
  k_graph_bounds<<<1, 512, 0, stream>>>(batch, gstart);
  k_pool<<<N_GRAPHS, 256, 0, stream>>>(h, embE, deg, gstart, gf);
  k_mlp0<<<N_GRAPHS, 256, 0, stream>>>(gf, W0, b0, m0);
  k_mlp1<<<(N_GRAPHS * OUT_DIM + 63) / 64, 64, 0, stream>>>(m0, W1, b1, out0);
}

// Round 2
// 1461.831 us; speedup vs baseline: 1.6053x; 1.6053x over previous
//
#include <hip/hip_runtime.h>
#include <cfloat>

#define N_NODES 50000
#define N_EDGES 600000
#define DIM 128
#define N_GRAPHS 256
#define HIDDEN 256
#define OUT_DIM 16
#define MAX_DEG 10
#define MAX_TBL 1600

// ---------------- CSR build ----------------
__global__ void k_deg_count(const int* __restrict__ col, int* __restrict__ deg) {
  int e = blockIdx.x * blockDim.x + threadIdx.x;
  if (e < N_EDGES) atomicAdd(&deg[col[e]], 1);
}

__global__ void k_scan(const int* __restrict__ deg, int* __restrict__ rowptr,
                       int* __restrict__ cursor) {
  __shared__ int tsum[1024];
  const int CH = (N_NODES + 1023) / 1024;  // 49
  int t = threadIdx.x;
  int lo = t * CH, hi = min(lo + CH, N_NODES);
  int s = 0;
  for (int i = lo; i < hi; ++i) s += deg[i];
  tsum[t] = s;
  __syncthreads();
  for (int off = 1; off < 1024; off <<= 1) {
    int v = (t >= off) ? tsum[t - off] : 0;
    __syncthreads();
    tsum[t] += v;
    __syncthreads();
  }
  int pre = (t == 0) ? 0 : tsum[t - 1];
  for (int i = lo; i < hi; ++i) { rowptr[i] = pre; cursor[i] = pre; pre += deg[i]; }
  if (t == 1023) rowptr[N_NODES] = tsum[1023];
}

__global__ void k_csr_scatter(const int* __restrict__ row, const int* __restrict__ col,
                              int* __restrict__ cursor, int* __restrict__ src) {
  int e = blockIdx.x * blockDim.x + threadIdx.x;
  if (e < N_EDGES) {
    int p = atomicAdd(&cursor[col[e]], 1);
    src[p] = row[e];
  }
}

// per-block LDS histogram -> 11 global atomics per block (was 256)
__global__ void k_bucket_count(const int* __restrict__ deg, int* __restrict__ bcnt) {
  __shared__ int lh[MAX_DEG + 1];
  int t = threadIdx.x;
  if (t <= MAX_DEG) lh[t] = 0;
  __syncthreads();
  int i = blockIdx.x * blockDim.x + t;
  if (i < N_NODES) atomicAdd(&lh[min(deg[i], MAX_DEG)], 1);
  __syncthreads();
  if (t <= MAX_DEG && lh[t]) atomicAdd(&bcnt[t], lh[t]);
}

__global__ void k_bucket_table(const int* __restrict__ bcnt, int* __restrict__ bcur,
                               int* __restrict__ tbl_d, int* __restrict__ tbl_base,
                               int* __restrict__ tbl_cnt) {
  if (threadIdx.x == 0 && blockIdx.x == 0) {
    int off = 0, nb = 0;
    for (int d = 0; d <= MAX_DEG; ++d) {
      bcur[d] = off;
      int c = bcnt[d];
      for (int s = 0; s < c; s += 32) {
        tbl_d[nb] = d; tbl_base[nb] = off + s; tbl_cnt[nb] = min(32, c - s); nb++;
      }
      off += c;
    }
    for (; nb < MAX_TBL; ++nb) tbl_d[nb] = -1;
  }
}

// local rank via LDS atomic, one global reservation per bucket per block
__global__ void k_node_scatter(const int* __restrict__ deg, int* __restrict__ bcur,
                               int* __restrict__ nlist) {
  __shared__ int lh[MAX_DEG + 1];
  __shared__ int gbase[MAX_DEG + 1];
  int t = threadIdx.x;
  if (t <= MAX_DEG) lh[t] = 0;
  __syncthreads();
  int i = blockIdx.x * blockDim.x + t;
  int b = 0, r = 0;
  if (i < N_NODES) { b = min(deg[i], MAX_DEG); r = atomicAdd(&lh[b], 1); }
  __syncthreads();
  if (t <= MAX_DEG) gbase[t] = lh[t] ? atomicAdd(&bcur[t], lh[t]) : 0;
  __syncthreads();
  if (i < N_NODES) nlist[gbase[b] + r] = i;
}

// ---------------- Aggregations ----------------
// h[i] = sum over incoming edges of (relu?)(x[src])
template <bool RELU>
__global__ void k_agg_sum(const float* __restrict__ x, const int* __restrict__ rowptr,
                          const int* __restrict__ src, float* __restrict__ h) {
  int node = blockIdx.x * 4 + (threadIdx.x >> 5);
  int l = threadIdx.x & 31;
  if (node >= N_NODES) return;
  int s = rowptr[node], e = rowptr[node + 1];
  float4 acc = make_float4(0.f, 0.f, 0.f, 0.f);
  for (int p = s; p < e; ++p) {
    const float4 v = ((const float4*)(x + (size_t)src[p] * DIM))[l];
    if (RELU) {
      acc.x += fmaxf(v.x, 0.f); acc.y += fmaxf(v.y, 0.f);
      acc.z += fmaxf(v.z, 0.f); acc.w += fmaxf(v.w, 0.f);
    } else {
      acc.x += v.x; acc.y += v.y; acc.z += v.z; acc.w += v.w;
    }
  }
  ((float4*)(h + (size_t)node * DIM))[l] = acc;
}

// out[i] = (deg==0) ? 0 : C[i] + b_edge + max_{incoming} B[src]
__global__ void k_edge_aggr(const float* __restrict__ Bm, const float* __restrict__ Cm,
                            const float* __restrict__ b_edge, const int* __restrict__ deg,
                            const int* __restrict__ rowptr, const int* __restrict__ src,
                            float* __restrict__ out) {
  int node = blockIdx.x * 4 + (threadIdx.x >> 5);
  int l = threadIdx.x & 31;
  if (node >= N_NODES) return;
  float4* o = (float4*)(out + (size_t)node * DIM);
  if (deg[node] == 0) { o[l] = make_float4(0.f, 0.f, 0.f, 0.f); return; }
  int s = rowptr[node], e = rowptr[node + 1];
  float4 m = make_float4(-FLT_MAX, -FLT_MAX, -FLT_MAX, -FLT_MAX);
  for (int p = s; p < e; ++p) {
    const float4 v = ((const float4*)(Bm + (size_t)src[p] * DIM))[l];
    m.x = fmaxf(m.x, v.x); m.y = fmaxf(m.y, v.y);
    m.z = fmaxf(m.z, v.z); m.w = fmaxf(m.w, v.w);
  }
  const float4 c = ((const float4*)(Cm + (size_t)node * DIM))[l];
  const float4 be = ((const float4*)b_edge)[l];
  o[l] = make_float4(c.x + be.x + m.x, c.y + be.y + m.y,
                     c.z + be.z + m.z, c.w + be.w + m.w);
}

// ---------------- MFConv matvec (degree-bucketed, 32 nodes / block) ----------------
template <bool RELUX>
__global__ __launch_bounds__(128) void k_mfconv(
    const float* __restrict__ h, const float* __restrict__ x,
    const float* __restrict__ W_lin, const float* __restrict__ b_lin,
    const float* __restrict__ W_root,
    const int* __restrict__ tbl_d, const int* __restrict__ tbl_base,
    const int* __restrict__ tbl_cnt, const int* __restrict__ nlist,
    float* __restrict__ out) {
  int b = blockIdx.x;
  int d = tbl_d[b];
  if (d < 0) return;
  int base = tbl_base[b], cnt = tbl_cnt[b];
  __shared__ float hs[32][DIM];
  __shared__ float xs[32][DIM];
  __shared__ int nid[32];
  int j = threadIdx.x;
  if (j < 32) nid[j] = nlist[base + min(j, cnt - 1)];
  __syncthreads();
#pragma unroll 4
  for (int i = 0; i < 32; ++i) {
    size_t r = (size_t)nid[i] * DIM + j;
    float hv = h[r], xv = x[r];
    if (RELUX) xv = fmaxf(xv, 0.f);
    hs[i][j] = hv; xs[i][j] = xv;
  }
  __syncthreads();
  const float* Wl = W_lin + (size_t)d * DIM * DIM + j;
  const float* Wr = W_root + (size_t)d * DIM * DIM + j;
  float bl = b_lin[d * DIM + j];
  float acc[32];
#pragma unroll
  for (int i = 0; i < 32; ++i) acc[i] = bl;
  for (int k = 0; k < DIM; k += 4) {
    float wl0 = Wl[(k + 0) * DIM], wl1 = Wl[(k + 1) * DIM];
    float wl2 = Wl[(k + 2) * DIM], wl3 = Wl[(k + 3) * DIM];
    float wr0 = Wr[(k + 0) * DIM], wr1 = Wr[(k + 1) * DIM];
    float wr2 = Wr[(k + 2) * DIM], wr3 = Wr[(k + 3) * DIM];
#pragma unroll
    for (int i = 0; i < 32; ++i) {
      float4 hv = *(const float4*)&hs[i][k];
      float4 xv = *(const float4*)&xs[i][k];
      acc[i] += hv.x * wl0 + hv.y * wl1 + hv.z * wl2 + hv.w * wl3 +
                xv.x * wr0 + xv.y * wr1 + xv.z * wr2 + xv.w * wr3;
    }
  }
  for (int i = 0; i < 32; ++i)
    if (i < cnt) out[(size_t)nid[i] * DIM + j] = acc[i];
}

// ---------------- EdgeConv GEMM: B = e@W_bot, C = e@(W_top - W_bot) ----------------
template <bool RELU>
__global__ __launch_bounds__(128) void k_edge_gemm(
    const float* __restrict__ e, const float* __restrict__ W,
    float* __restrict__ Bm, float* __restrict__ Cm) {
  int base = blockIdx.x * 32;
  int j = threadIdx.x;
  int cnt = min(32, N_NODES - base);
  __shared__ float es[32][DIM];
#pragma unroll 4
  for (int i = 0; i < 32; ++i) {
    int r = base + min(i, cnt - 1);
    float v = e[(size_t)r * DIM + j];
    if (RELU) v = fmaxf(v, 0.f);
    es[i][j] = v;
  }
  __syncthreads();
  float accB[32], accC[32];
#pragma unroll
  for (int i = 0; i < 32; ++i) { accB[i] = 0.f; accC[i] = 0.f; }
  const float* Wt = W + j;              // rows [0,128)   = W_top
  const float* Wb = W + 128 * DIM + j;  // rows [128,256) = W_bot
  for (int k = 0; k < DIM; k += 4) {
    float wb0 = Wb[(k + 0) * DIM], wb1 = Wb[(k + 1) * DIM];
    float wb2 = Wb[(k + 2) * DIM], wb3 = Wb[(k + 3) * DIM];
    float wd0 = Wt[(k + 0) * DIM] - wb0, wd1 = Wt[(k + 1) * DIM] - wb1;
    float wd2 = Wt[(k + 2) * DIM] - wb2, wd3 = Wt[(k + 3) * DIM] - wb3;
#pragma unroll
    for (int i = 0; i < 32; ++i) {
      float4 ev = *(const float4*)&es[i][k];
      accB[i] += ev.x * wb0 + ev.y * wb1 + ev.z * wb2 + ev.w * wb3;
      accC[i] += ev.x * wd0 + ev.y * wd1 + ev.z * wd2 + ev.w * wd3;
    }
  }
  for (int i = 0; i < 32; ++i)
    if (i < cnt) {
      Bm[(size_t)(base + i) * DIM + j] = accB[i];
      Cm[(size_t)(base + i) * DIM + j] = accC[i];
    }
}

// ---------------- Readout ----------------
__global__ void k_graph_bounds(const int* __restrict__ batch, int* __restrict__ gstart) {
  int g = blockIdx.x * blockDim.x + threadIdx.x;
  if (g > N_GRAPHS) return;
  int lo = 0, hi = N_NODES;
  while (lo < hi) {
    int mid = (lo + hi) >> 1;
    if (batch[mid] < g) lo = mid + 1; else hi = mid;
  }
  gstart[g] = lo;
}

__global__ void k_pool(const float* __restrict__ hf, const float* __restrict__ embE,
                       const int* __restrict__ deg, const int* __restrict__ gstart,
                       float* __restrict__ gf) {
  int g = blockIdx.x;
  int j = threadIdx.x;  // 256
  int s = gstart[g], e = gstart[g + 1];
  float acc = 0.f;
  if (j < DIM) {
    for (int i = s; i < e; ++i) acc += hf[(size_t)i * DIM + j];
  } else {
    int jj = j - DIM;
    for (int i = s; i < e; ++i)
      acc += (float)deg[i] * fmaxf(embE[(size_t)i * DIM + jj], 0.f);
  }
  gf[g * 256 + j] = acc;
}

__global__ void k_mlp0(const float* __restrict__ gf, const float* __restrict__ W0,
                       const float* __restrict__ b0, float* __restrict__ o) {
  int g = blockIdx.x, j = threadIdx.x;  // 256
  __shared__ float gs[256];
  gs[j] = gf[g * 256 + j];
  __syncthreads();
  float acc = b0[j];
  for (int k = 0; k < 256; ++k) acc += gs[k] * W0[k * 256 + j];
  o[g * 256 + j] = fmaxf(acc, 0.f);
}

__global__ void k_mlp1(const float* __restrict__ m0, const float* __restrict__ W1,
                       const float* __restrict__ b1, float* __restrict__ out) {
  int idx = blockIdx.x * 64 + threadIdx.x;
  if (idx >= N_GRAPHS * OUT_DIM) return;
  int g = idx >> 4, j = idx & 15;
  float acc = b1[j];
  const float* mr = m0 + g * HIDDEN;
  for (int k = 0; k < HIDDEN; ++k) acc += mr[k] * W1[k * OUT_DIM + j];
  out[idx] = fmaxf(acc, 0.f);
}

// ---------------- launch ----------------
extern "C" void kernel_launch(void* const* d_in, const int* in_sizes, int n_in,
                              void* d_out, int out_size, void* d_ws, size_t ws_size,
                              hipStream_t stream) {
  const float* x_in   = (const float*)d_in[0];
  const float* ea_in  = (const float*)d_in[1];
  const int*   ei     = (const int*)d_in[2];
  const int*   batch  = (const int*)d_in[3];
  const float* W_lin  = (const float*)d_in[4];
  const float* b_lin  = (const float*)d_in[5];
  const float* W_root = (const float*)d_in[6];
  const float* W_edge = (const float*)d_in[7];
  const float* b_edge = (const float*)d_in[8];
  const float* W0     = (const float*)d_in[9];
  const float* b0     = (const float*)d_in[10];
  const float* W1     = (const float*)d_in[11];
  const float* b1     = (const float*)d_in[12];
  const int* row = ei;
  const int* col = ei + N_EDGES;

  float* out0 = (float*)d_out;                  // [256,16]
  float* embN = out0 + N_GRAPHS * OUT_DIM;      // [50000,128] pre-relu MFConv out (iter 2)
  float* embE = embN + (size_t)N_NODES * DIM;   // [600000,128] pre-relu EdgeConv out (iter 2)

  char* wsp = (char*)d_ws;
  auto alloc = [&](size_t bytes) {
    char* p = wsp;
    wsp += (bytes + 255) & ~(size_t)255;
    return p;
  };
  int* deg      = (int*)alloc((size_t)N_NODES * 4);
  int* rowptr   = (int*)alloc((size_t)(N_NODES + 1) * 4);
  int* cursor   = (int*)alloc((size_t)N_NODES * 4);
  int* src      = (int*)alloc((size_t)N_EDGES * 4);
  int* nlist    = (int*)alloc((size_t)N_NODES * 4);
  int* bcnt     = (int*)alloc(16 * 4);
  int* bcur     = (int*)alloc(16 * 4);
  int* tbl_d    = (int*)alloc(MAX_TBL * 4);
  int* tbl_base = (int*)alloc(MAX_TBL * 4);
  int* tbl_cnt  = (int*)alloc(MAX_TBL * 4);
  int* gstart   = (int*)alloc(257 * 4);
  float* h      = (float*)alloc((size_t)N_NODES * DIM * 4);  // reused as h_final
  float* Bm     = (float*)alloc((size_t)N_NODES * DIM * 4);
  float* Cm     = (float*)alloc((size_t)N_NODES * DIM * 4);
  float* gf     = (float*)alloc((size_t)N_GRAPHS * 256 * 4);
  float* m0     = (float*)alloc((size_t)N_GRAPHS * HIDDEN * 4);

  hipMemsetAsync(deg, 0, (size_t)N_NODES * 4, stream);
  hipMemsetAsync(bcnt, 0, 16 * 4, stream);
  // emb_edge rows [50000, 600000) are exactly 0 (empty segment-max -> where -> 0)
  hipMemsetAsync(embE + (size_t)N_NODES * DIM, 0,
                 (size_t)(N_EDGES - N_NODES) * DIM * sizeof(float), stream);

  const int EB = (N_EDGES + 255) / 256;
  const int NB = (N_NODES + 255) / 256;
  k_deg_count<<<EB, 256, 0, stream>>>(col, deg);
  k_scan<<<1, 1024, 0, stream>>>(deg, rowptr, cursor);
  k_csr_scatter<<<EB, 256, 0, stream>>>(row, col, cursor, src);
  k_bucket_count<<<NB, 256, 0, stream>>>(deg, bcnt);
  k_bucket_table<<<1, 64, 0, stream>>>(bcnt, bcur, tbl_d, tbl_base, tbl_cnt);
  k_node_scatter<<<NB, 256, 0, stream>>>(deg, bcur, nlist);

  const int AGG_GRID = (N_NODES + 3) / 4;
  const int GEMM_GRID = (N_NODES + 31) / 32;
  // ---- message pass 0 ----
  k_agg_sum<false><<<AGG_GRID, 128, 0, stream>>>(x_in, rowptr, src, h);
  k_mfconv<false><<<MAX_TBL, 128, 0, stream>>>(h, x_in, W_lin, b_lin, W_root,
                                               tbl_d, tbl_base, tbl_cnt, nlist, embN);
  k_edge_gemm<false><<<GEMM_GRID, 128, 0, stream>>>(ea_in, W_edge, Bm, Cm);
  k_edge_aggr<<<AGG_GRID, 128, 0, stream>>>(Bm, Cm, b_edge, deg, rowptr, src, embE);
  // ---- message pass 1 (relu on read; in-place on d_out regions is block-local safe) ----
  k_agg_sum<true><<<AGG_GRID, 128, 0, stream>>>(embN, rowptr, src, h);
  k_mfconv<true><<<MAX_TBL, 128, 0, stream>>>(h, embN, W_lin, b_lin, W_root,
                                              tbl_d, tbl_base, tbl_cnt, nlist, embN);
  k_edge_gemm<true><<<GEMM_GRID, 128, 0, stream>>>(embE, W_edge, Bm, Cm);
  k_edge_aggr<<<AGG_GRID, 128, 0, stream>>>(Bm, Cm, b_edge, deg, rowptr, src, embE);
  // ---- readout ----
  k_agg_sum<true><<<AGG_GRID, 128, 0, stream>>>(embN, rowptr, src, h);
  k_graph_bounds<<<1, 512, 0, stream>>>(batch, gstart);
  k_pool<<<N_GRAPHS, 256, 0, stream>>>(h, embE, deg, gstart, gf);
  k_mlp0<<<N_GRAPHS, 256, 0, stream>>>(gf, W0, b0, m0);
  k_mlp1<<<(N_GRAPHS * OUT_DIM + 63) / 64, 64, 0, stream>>>(m0, W1, b1, out0);
}

// Round 3
// 1435.042 us; speedup vs baseline: 1.6353x; 1.0187x over previous
//
#include <hip/hip_runtime.h>
#include <cfloat>

#define N_NODES 50000
#define N_EDGES 600000
#define DIM 128
#define N_GRAPHS 256
#define HIDDEN 256
#define OUT_DIM 16
#define MAX_DEG 10
#define MAX_TBL 1600

__device__ __forceinline__ float4 relu4(float4 v) {
  return make_float4(fmaxf(v.x, 0.f), fmaxf(v.y, 0.f), fmaxf(v.z, 0.f), fmaxf(v.w, 0.f));
}
__device__ __forceinline__ void add4(float4& a, const float4 v) {
  a.x += v.x; a.y += v.y; a.z += v.z; a.w += v.w;
}
__device__ __forceinline__ void fma4(float4& a, float m, const float4 v) {
  a.x = fmaf(m, v.x, a.x); a.y = fmaf(m, v.y, a.y);
  a.z = fmaf(m, v.z, a.z); a.w = fmaf(m, v.w, a.w);
}
__device__ __forceinline__ void max4(float4& a, const float4 v) {
  a.x = fmaxf(a.x, v.x); a.y = fmaxf(a.y, v.y);
  a.z = fmaxf(a.z, v.z); a.w = fmaxf(a.w, v.w);
}

// ---------------- CSR build ----------------
__global__ void k_deg_count(const int* __restrict__ col, int* __restrict__ deg) {
  int e = blockIdx.x * blockDim.x + threadIdx.x;
  if (e < N_EDGES) atomicAdd(&deg[col[e]], 1);
}

__global__ void k_scan(const int* __restrict__ deg, int* __restrict__ rowptr,
                       int* __restrict__ cursor) {
  __shared__ int tsum[1024];
  const int CH = (N_NODES + 1023) / 1024;  // 49
  int t = threadIdx.x;
  int lo = t * CH, hi = min(lo + CH, N_NODES);
  int s = 0;
  for (int i = lo; i < hi; ++i) s += deg[i];
  tsum[t] = s;
  __syncthreads();
  for (int off = 1; off < 1024; off <<= 1) {
    int v = (t >= off) ? tsum[t - off] : 0;
    __syncthreads();
    tsum[t] += v;
    __syncthreads();
  }
  int pre = (t == 0) ? 0 : tsum[t - 1];
  for (int i = lo; i < hi; ++i) { rowptr[i] = pre; cursor[i] = pre; pre += deg[i]; }
  if (t == 1023) rowptr[N_NODES] = tsum[1023];
}

__global__ void k_csr_scatter(const int* __restrict__ row, const int* __restrict__ col,
                              int* __restrict__ cursor, int* __restrict__ src) {
  int e = blockIdx.x * blockDim.x + threadIdx.x;
  if (e < N_EDGES) {
    int p = atomicAdd(&cursor[col[e]], 1);
    src[p] = row[e];
  }
}

__global__ void k_bucket_count(const int* __restrict__ deg, int* __restrict__ bcnt) {
  __shared__ int lh[MAX_DEG + 1];
  int t = threadIdx.x;
  if (t <= MAX_DEG) lh[t] = 0;
  __syncthreads();
  int i = blockIdx.x * blockDim.x + t;
  if (i < N_NODES) atomicAdd(&lh[min(deg[i], MAX_DEG)], 1);
  __syncthreads();
  if (t <= MAX_DEG && lh[t]) atomicAdd(&bcnt[t], lh[t]);
}

__global__ void k_bucket_table(const int* __restrict__ bcnt, int* __restrict__ bcur,
                               int* __restrict__ tbl_d, int* __restrict__ tbl_base,
                               int* __restrict__ tbl_cnt) {
  if (threadIdx.x == 0 && blockIdx.x == 0) {
    int off = 0, nb = 0;
    for (int d = 0; d <= MAX_DEG; ++d) {
      bcur[d] = off;
      int c = bcnt[d];
      for (int s = 0; s < c; s += 32) {
        tbl_d[nb] = d; tbl_base[nb] = off + s; tbl_cnt[nb] = min(32, c - s); nb++;
      }
      off += c;
    }
    for (; nb < MAX_TBL; ++nb) tbl_d[nb] = -1;
  }
}

__global__ void k_node_scatter(const int* __restrict__ deg, int* __restrict__ bcur,
                               int* __restrict__ nlist) {
  __shared__ int lh[MAX_DEG + 1];
  __shared__ int gbase[MAX_DEG + 1];
  int t = threadIdx.x;
  if (t <= MAX_DEG) lh[t] = 0;
  __syncthreads();
  int i = blockIdx.x * blockDim.x + t;
  int b = 0, r = 0;
  if (i < N_NODES) { b = min(deg[i], MAX_DEG); r = atomicAdd(&lh[b], 1); }
  __syncthreads();
  if (t <= MAX_DEG) gbase[t] = lh[t] ? atomicAdd(&bcur[t], lh[t]) : 0;
  __syncthreads();
  if (i < N_NODES) nlist[gbase[b] + r] = i;
}

// ---------------- Fused MFConv: gather-sum neighbors + degree-bucketed matvec ----------------
template <bool RELU>
__global__ __launch_bounds__(128) void kMF_fused(
    const float* __restrict__ x, const float* __restrict__ W_lin,
    const float* __restrict__ b_lin, const float* __restrict__ W_root,
    const int* __restrict__ rowptr, const int* __restrict__ src,
    const int* __restrict__ tbl_d, const int* __restrict__ tbl_base,
    const int* __restrict__ tbl_cnt, const int* __restrict__ nlist,
    float* __restrict__ out) {
  int b = blockIdx.x;
  int d = tbl_d[b];
  if (d < 0) return;
  int base = tbl_base[b], cnt = tbl_cnt[b];
  __shared__ float hs[32][DIM];
  __shared__ float xs[32][DIM];
  __shared__ int nid[32];
  int j = threadIdx.x;
  if (j < 32) nid[j] = nlist[base + min(j, cnt - 1)];
  __syncthreads();
  int q = j >> 5, l = j & 31;
  // gather phase: 32-lane group q handles nodes i = q, q+4, ... (8 nodes)
  for (int i = q; i < 32; i += 4) {
    int node = nid[i];
    int s = rowptr[node], e = rowptr[node + 1];
    float4 a = make_float4(0.f, 0.f, 0.f, 0.f);
    // unroll-4 with clamped idx + 0/1 mask: 4 row loads in flight
    for (int p = s; p < e; p += 4) {
      int e1 = e - 1;
      int i0 = src[p], i1 = src[min(p + 1, e1)];
      int i2 = src[min(p + 2, e1)], i3 = src[min(p + 3, e1)];
      float4 v0 = ((const float4*)(x + (size_t)i0 * DIM))[l];
      float4 v1 = ((const float4*)(x + (size_t)i1 * DIM))[l];
      float4 v2 = ((const float4*)(x + (size_t)i2 * DIM))[l];
      float4 v3 = ((const float4*)(x + (size_t)i3 * DIM))[l];
      if (RELU) { v0 = relu4(v0); v1 = relu4(v1); v2 = relu4(v2); v3 = relu4(v3); }
      add4(a, v0);
      fma4(a, (p + 1 < e) ? 1.f : 0.f, v1);
      fma4(a, (p + 2 < e) ? 1.f : 0.f, v2);
      fma4(a, (p + 3 < e) ? 1.f : 0.f, v3);
    }
    float4 xv = ((const float4*)(x + (size_t)node * DIM))[l];
    if (RELU) xv = relu4(xv);
    ((float4*)&hs[i][0])[l] = a;
    ((float4*)&xs[i][0])[l] = xv;
  }
  __syncthreads();
  // matvec phase: thread j computes output column j for all 32 nodes
  const float* Wl = W_lin + (size_t)d * DIM * DIM + j;
  const float* Wr = W_root + (size_t)d * DIM * DIM + j;
  float bl = b_lin[d * DIM + j];
  float acc[32];
#pragma unroll
  for (int i = 0; i < 32; ++i) acc[i] = bl;
  for (int k = 0; k < DIM; k += 4) {
    float wl0 = Wl[(k + 0) * DIM], wl1 = Wl[(k + 1) * DIM];
    float wl2 = Wl[(k + 2) * DIM], wl3 = Wl[(k + 3) * DIM];
    float wr0 = Wr[(k + 0) * DIM], wr1 = Wr[(k + 1) * DIM];
    float wr2 = Wr[(k + 2) * DIM], wr3 = Wr[(k + 3) * DIM];
#pragma unroll
    for (int i = 0; i < 32; ++i) {
      float4 hv = *(const float4*)&hs[i][k];   // LDS broadcast (same addr all lanes)
      float4 xv = *(const float4*)&xs[i][k];
      acc[i] += hv.x * wl0 + hv.y * wl1 + hv.z * wl2 + hv.w * wl3 +
                xv.x * wr0 + xv.y * wr1 + xv.z * wr2 + xv.w * wr3;
    }
  }
  for (int i = 0; i < 32; ++i)
    if (i < cnt) out[(size_t)nid[i] * DIM + j] = acc[i];
}

// ---------------- EdgeConv GEMM: B = e@W_bot, C = e@(W_top - W_bot) ----------------
template <bool RELU>
__global__ __launch_bounds__(128) void kEG_gemm(
    const float* __restrict__ e, const float* __restrict__ W,
    float* __restrict__ Bm, float* __restrict__ Cm) {
  int base = blockIdx.x * 32;
  int j = threadIdx.x;
  int cnt = min(32, N_NODES - base);
  __shared__ float es[32][DIM];
#pragma unroll 4
  for (int i = 0; i < 32; ++i) {
    int r = base + min(i, cnt - 1);
    float v = e[(size_t)r * DIM + j];
    if (RELU) v = fmaxf(v, 0.f);
    es[i][j] = v;
  }
  __syncthreads();
  float accB[32], accC[32];
#pragma unroll
  for (int i = 0; i < 32; ++i) { accB[i] = 0.f; accC[i] = 0.f; }
  const float* Wt = W + j;              // rows [0,128)   = W_top
  const float* Wb = W + 128 * DIM + j;  // rows [128,256) = W_bot
  for (int k = 0; k < DIM; k += 4) {
    float wb0 = Wb[(k + 0) * DIM], wb1 = Wb[(k + 1) * DIM];
    float wb2 = Wb[(k + 2) * DIM], wb3 = Wb[(k + 3) * DIM];
    float wd0 = Wt[(k + 0) * DIM] - wb0, wd1 = Wt[(k + 1) * DIM] - wb1;
    float wd2 = Wt[(k + 2) * DIM] - wb2, wd3 = Wt[(k + 3) * DIM] - wb3;
#pragma unroll
    for (int i = 0; i < 32; ++i) {
      float4 ev = *(const float4*)&es[i][k];
      accB[i] += ev.x * wb0 + ev.y * wb1 + ev.z * wb2 + ev.w * wb3;
      accC[i] += ev.x * wd0 + ev.y * wd1 + ev.z * wd2 + ev.w * wd3;
    }
  }
  for (int i = 0; i < 32; ++i)
    if (i < cnt) {
      Bm[(size_t)(base + i) * DIM + j] = accB[i];
      Cm[(size_t)(base + i) * DIM + j] = accC[i];
    }
}

// out[i] = (deg==0) ? 0 : C[i] + b_edge + max_{incoming} B[src]
__global__ void kEA_aggr(const float* __restrict__ Bm, const float* __restrict__ Cm,
                         const float* __restrict__ b_edge, const int* __restrict__ deg,
                         const int* __restrict__ rowptr, const int* __restrict__ src,
                         float* __restrict__ out) {
  int node = blockIdx.x * 4 + (threadIdx.x >> 5);
  int l = threadIdx.x & 31;
  if (node >= N_NODES) return;
  float4* o = (float4*)(out + (size_t)node * DIM);
  if (deg[node] == 0) { o[l] = make_float4(0.f, 0.f, 0.f, 0.f); return; }
  int s = rowptr[node], e = rowptr[node + 1];
  const float4 c = ((const float4*)(Cm + (size_t)node * DIM))[l];
  const float4 be = ((const float4*)b_edge)[l];
  float4 m = make_float4(-FLT_MAX, -FLT_MAX, -FLT_MAX, -FLT_MAX);
  for (int p = s; p < e; p += 4) {  // max is idempotent: clamped dup loads are free
    int e1 = e - 1;
    int i0 = src[p], i1 = src[min(p + 1, e1)];
    int i2 = src[min(p + 2, e1)], i3 = src[min(p + 3, e1)];
    float4 v0 = ((const float4*)(Bm + (size_t)i0 * DIM))[l];
    float4 v1 = ((const float4*)(Bm + (size_t)i1 * DIM))[l];
    float4 v2 = ((const float4*)(Bm + (size_t)i2 * DIM))[l];
    float4 v3 = ((const float4*)(Bm + (size_t)i3 * DIM))[l];
    max4(m, v0); max4(m, v1); max4(m, v2); max4(m, v3);
  }
  o[l] = make_float4(c.x + be.x + m.x, c.y + be.y + m.y,
                     c.z + be.z + m.z, c.w + be.w + m.w);
}

// h_final[i] = sum relu(x[src]) for readout
__global__ void kA_final(const float* __restrict__ x, const int* __restrict__ rowptr,
                         const int* __restrict__ src, float* __restrict__ h) {
  int node = blockIdx.x * 4 + (threadIdx.x >> 5);
  int l = threadIdx.x & 31;
  if (node >= N_NODES) return;
  int s = rowptr[node], e = rowptr[node + 1];
  float4 a = make_float4(0.f, 0.f, 0.f, 0.f);
  for (int p = s; p < e; p += 4) {
    int e1 = e - 1;
    int i0 = src[p], i1 = src[min(p + 1, e1)];
    int i2 = src[min(p + 2, e1)], i3 = src[min(p + 3, e1)];
    float4 v0 = relu4(((const float4*)(x + (size_t)i0 * DIM))[l]);
    float4 v1 = relu4(((const float4*)(x + (size_t)i1 * DIM))[l]);
    float4 v2 = relu4(((const float4*)(x + (size_t)i2 * DIM))[l]);
    float4 v3 = relu4(((const float4*)(x + (size_t)i3 * DIM))[l]);
    add4(a, v0);
    fma4(a, (p + 1 < e) ? 1.f : 0.f, v1);
    fma4(a, (p + 2 < e) ? 1.f : 0.f, v2);
    fma4(a, (p + 3 < e) ? 1.f : 0.f, v3);
  }
  ((float4*)(h + (size_t)node * DIM))[l] = a;
}

// ---------------- Readout ----------------
__global__ void k_graph_bounds(const int* __restrict__ batch, int* __restrict__ gstart) {
  int g = blockIdx.x * blockDim.x + threadIdx.x;
  if (g > N_GRAPHS) return;
  int lo = 0, hi = N_NODES;
  while (lo < hi) {
    int mid = (lo + hi) >> 1;
    if (batch[mid] < g) lo = mid + 1; else hi = mid;
  }
  gstart[g] = lo;
}

__global__ void k_pool(const float* __restrict__ hf, const float* __restrict__ embE,
                       const int* __restrict__ deg, const int* __restrict__ gstart,
                       float* __restrict__ gf) {
  int g = blockIdx.x;
  int j = threadIdx.x;  // 256
  int s = gstart[g], e = gstart[g + 1];
  float acc = 0.f;
  if (j < DIM) {
    for (int i = s; i < e; ++i) acc += hf[(size_t)i * DIM + j];
  } else {
    int jj = j - DIM;
    for (int i = s; i < e; ++i)
      acc += (float)deg[i] * fmaxf(embE[(size_t)i * DIM + jj], 0.f);
  }
  gf[g * 256 + j] = acc;
}

__global__ void k_mlp0(const float* __restrict__ gf, const float* __restrict__ W0,
                       const float* __restrict__ b0, float* __restrict__ o) {
  int g = blockIdx.x, j = threadIdx.x;  // 256
  __shared__ float gs[256];
  gs[j] = gf[g * 256 + j];
  __syncthreads();
  float acc = b0[j];
  for (int k = 0; k < 256; ++k) acc += gs[k] * W0[k * 256 + j];
  o[g * 256 + j] = fmaxf(acc, 0.f);
}

__global__ void k_mlp1(const float* __restrict__ m0, const float* __restrict__ W1,
                       const float* __restrict__ b1, float* __restrict__ out) {
  int idx = blockIdx.x * 64 + threadIdx.x;
  if (idx >= N_GRAPHS * OUT_DIM) return;
  int g = idx >> 4, j = idx & 15;
  float acc = b1[j];
  const float* mr = m0 + g * HIDDEN;
  for (int k = 0; k < HIDDEN; ++k) acc += mr[k] * W1[k * OUT_DIM + j];
  out[idx] = fmaxf(acc, 0.f);
}

// ---------------- launch ----------------
extern "C" void kernel_launch(void* const* d_in, const int* in_sizes, int n_in,
                              void* d_out, int out_size, void* d_ws, size_t ws_size,
                              hipStream_t stream) {
  const float* x_in   = (const float*)d_in[0];
  const float* ea_in  = (const float*)d_in[1];
  const int*   ei     = (const int*)d_in[2];
  const int*   batch  = (const int*)d_in[3];
  const float* W_lin  = (const float*)d_in[4];
  const float* b_lin  = (const float*)d_in[5];
  const float* W_root = (const float*)d_in[6];
  const float* W_edge = (const float*)d_in[7];
  const float* b_edge = (const float*)d_in[8];
  const float* W0     = (const float*)d_in[9];
  const float* b0     = (const float*)d_in[10];
  const float* W1     = (const float*)d_in[11];
  const float* b1     = (const float*)d_in[12];
  const int* row = ei;
  const int* col = ei + N_EDGES;

  float* out0 = (float*)d_out;                  // [256,16]
  float* embN = out0 + N_GRAPHS * OUT_DIM;      // [50000,128] final pre-relu MFConv out
  float* embE = embN + (size_t)N_NODES * DIM;   // [600000,128] final pre-relu EdgeConv out

  char* wsp = (char*)d_ws;
  auto alloc = [&](size_t bytes) {
    char* p = wsp;
    wsp += (bytes + 255) & ~(size_t)255;
    return p;
  };
  int* deg      = (int*)alloc((size_t)N_NODES * 4);
  int* rowptr   = (int*)alloc((size_t)(N_NODES + 1) * 4);
  int* cursor   = (int*)alloc((size_t)N_NODES * 4);
  int* src      = (int*)alloc((size_t)N_EDGES * 4);
  int* nlist    = (int*)alloc((size_t)N_NODES * 4);
  int* bcnt     = (int*)alloc(16 * 4);
  int* bcur     = (int*)alloc(16 * 4);
  int* tbl_d    = (int*)alloc(MAX_TBL * 4);
  int* tbl_base = (int*)alloc(MAX_TBL * 4);
  int* tbl_cnt  = (int*)alloc(MAX_TBL * 4);
  int* gstart   = (int*)alloc(257 * 4);
  float* tmpN   = (float*)alloc((size_t)N_NODES * DIM * 4);  // pass0 MFConv out
  float* Em0    = (float*)alloc((size_t)N_NODES * DIM * 4);  // pass0 EdgeConv out
  float* Bm     = (float*)alloc((size_t)N_NODES * DIM * 4);
  float* Cm     = (float*)alloc((size_t)N_NODES * DIM * 4);
  float* h      = (float*)alloc((size_t)N_NODES * DIM * 4);  // readout node gather
  float* gf     = (float*)alloc((size_t)N_GRAPHS * 256 * 4);
  float* m0     = (float*)alloc((size_t)N_GRAPHS * HIDDEN * 4);

  hipMemsetAsync(deg, 0, (size_t)N_NODES * 4, stream);
  hipMemsetAsync(bcnt, 0, 16 * 4, stream);
  // emb_edge rows [50000, 600000) are exactly 0 (empty segment-max -> where -> 0)
  hipMemsetAsync(embE + (size_t)N_NODES * DIM, 0,
                 (size_t)(N_EDGES - N_NODES) * DIM * sizeof(float), stream);

  const int EB = (N_EDGES + 255) / 256;
  const int NB = (N_NODES + 255) / 256;
  k_deg_count<<<EB, 256, 0, stream>>>(col, deg);
  k_scan<<<1, 1024, 0, stream>>>(deg, rowptr, cursor);
  k_csr_scatter<<<EB, 256, 0, stream>>>(row, col, cursor, src);
  k_bucket_count<<<NB, 256, 0, stream>>>(deg, bcnt);
  k_bucket_table<<<1, 64, 0, stream>>>(bcnt, bcur, tbl_d, tbl_base, tbl_cnt);
  k_node_scatter<<<NB, 256, 0, stream>>>(deg, bcur, nlist);
  k_graph_bounds<<<1, 512, 0, stream>>>(batch, gstart);

  const int AGG_GRID = (N_NODES + 3) / 4;
  const int GEMM_GRID = (N_NODES + 31) / 32;
  // ---- message pass 0 ----
  kMF_fused<false><<<MAX_TBL, 128, 0, stream>>>(x_in, W_lin, b_lin, W_root,
                                                rowptr, src, tbl_d, tbl_base, tbl_cnt,
                                                nlist, tmpN);
  kEG_gemm<false><<<GEMM_GRID, 128, 0, stream>>>(ea_in, W_edge, Bm, Cm);
  kEA_aggr<<<AGG_GRID, 128, 0, stream>>>(Bm, Cm, b_edge, deg, rowptr, src, Em0);
  // ---- message pass 1 (relu applied on read; ping-pong buffers, no in-place race) ----
  kMF_fused<true><<<MAX_TBL, 128, 0, stream>>>(tmpN, W_lin, b_lin, W_root,
                                               rowptr, src, tbl_d, tbl_base, tbl_cnt,
                                               nlist, embN);
  kEG_gemm<true><<<GEMM_GRID, 128, 0, stream>>>(Em0, W_edge, Bm, Cm);
  kEA_aggr<<<AGG_GRID, 128, 0, stream>>>(Bm, Cm, b_edge, deg, rowptr, src, embE);
  // ---- readout ----
  kA_final<<<AGG_GRID, 128, 0, stream>>>(embN, rowptr, src, h);
  k_pool<<<N_GRAPHS, 256, 0, stream>>>(h, embE, deg, gstart, gf);
  k_mlp0<<<N_GRAPHS, 256, 0, stream>>>(gf, W0, b0, m0);
  k_mlp1<<<(N_GRAPHS * OUT_DIM + 63) / 64, 64, 0, stream>>>(m0, W1, b1, out0);
}